// Round 1
// baseline (182.644 us; speedup 1.0000x reference)
//
#include <hip/hip_runtime.h>
#include <math.h>

// Problem constants (from reference): B=8, Cin=32, Cout=32, S=256,
// REGION=64, OVERLAP=0 -> 4x4 regions, MAX_M=16.
#define NB 8
#define CIN 32
#define COUT 32
#define SS 256
#define REG 64
#define NMAX 16

// Workspace layout (bytes):
#define AVG_OFF   0
#define C64_OFF   4096
#define CN_OFF    4352
#define Y_OFF     8192
#define XE_OFF    (8u << 20)
#define XO_OFF    (12u << 20)
#define Z_OFF     (16u << 20)

// Per-block recomputation of the region's mode count n.
// MUST be bit-identical to the old k_nm sequence so every consumer agrees.
__device__ __forceinline__ int region_n(const float* __restrict__ avg, int r, int b) {
    float mn = avg[r * 8], mx = mn;
    for (int bb = 1; bb < NB; ++bb) {
        float v = avg[r * 8 + bb];
        mn = fminf(mn, v);
        mx = fmaxf(mx, v);
    }
    float d = mx - mn;
    bool ok = ((double)d > 1e-8);
    float norm = ok ? (avg[r * 8 + b] - mn) / d : 0.0f;
    float tt = norm * 15.0f;
    int nv = (int)tt + 1;
    return nv > NMAX ? NMAX : nv;
}

// grid (17, NB): blocks (r<16, b) do the region means; block (16, 0) builds
// the cas tables (one cos+sin pair per thread). Removes two tiny kernels
// (k_tables, k_nm) from the critical path.
__global__ void k_avg(const float* __restrict__ err, float* __restrict__ avg,
                      float* __restrict__ cyc64, float* __restrict__ cycN) {
    int t = threadIdx.x;
    if (blockIdx.x == 16) {
        if (blockIdx.y != 0) return;
        if (t < 64) {
            double a = (2.0 * M_PI / 64.0) * (double)t;
            cyc64[t] = (float)(cos(a) + sin(a));
        } else if (t < 64 + 136) {
            int e = t - 64;
            int n = 1;
            while (n * (n + 1) / 2 <= e) ++n;
            int j = e - n * (n - 1) / 2;
            double a = (2.0 * M_PI / (double)n) * (double)j;
            cycN[e] = (float)(cos(a) + sin(a));
        }
        return;
    }
    int r = blockIdx.x, b = blockIdx.y;
    int ri = r >> 2, rj = r & 3;
    const float* base = err + ((size_t)b * SS + ri * REG) * SS + rj * REG;
    double s = 0.0;
    for (int it = 0; it < 16; ++it) {
        int u = it * 4 + (t >> 6);
        int v = t & 63;
        s += (double)base[(size_t)u * SS + v];
    }
    __shared__ double sm[256];
    sm[t] = s;
    __syncthreads();
    for (int w = 128; w > 0; w >>= 1) {
        if (t < w) sm[t] += sm[t + w];
        __syncthreads();
    }
    if (t == 0) avg[r * 8 + b] = (float)(sm[0] / 4096.0);
}

// One block per (i, r, b): n-corner separable DHT of the 64x64 region, then
// true n x n dht2 via row-column + correction, then Xe/Xo split. 256 threads.
// Stage 1 is u-quarter-split: every wave active for every n, R read once per
// quarter (4x fewer ds_read_b128 wave-instrs), 4-way LDS reduction reusing R.
__global__ void k_fwd(const float* __restrict__ x, const float* __restrict__ avg,
                      const float* __restrict__ cyc64, const float* __restrict__ cycN,
                      float* __restrict__ Xe, float* __restrict__ Xo) {
    int i = blockIdx.x, r = blockIdx.y, b = blockIdx.z;
    int n = region_n(avg, r, b);
    int nn = n * n;
    int ri = r >> 2, rj = r & 3;
    int t = threadIdx.x;

    __shared__ __align__(16) float R[64 * 64];      // reused as partial buffer P
    __shared__ __align__(16) float M1[16 * 68];
    __shared__ float H[256];
    __shared__ float T1[256];
    __shared__ float T2[256];
    __shared__ float cyc64L[64];
    __shared__ float cnL[16];

    if (t < 64) cyc64L[t] = cyc64[t];
    if (t < n)  cnL[t] = cycN[(n * (n - 1)) / 2 + t];

    const float* base = x + (((size_t)(b * CIN + i)) * SS + ri * REG) * SS + rj * REG;
    float4* R4 = (float4*)R;
    {
        int u0 = t >> 4, c4 = t & 15;
        for (int it = 0; it < 4; ++it) {
            int u = it * 16 + u0;
            R4[u * 16 + c4] = *(const float4*)(base + (size_t)u * SS + c4 * 4);
        }
    }
    __syncthreads();

    // stage 1: M1[p][v] = sum_u cas64(p*u) * R[u][v], p < n.
    // thread = (uq = t>>6, ps = (t>>4)&3, vg = t&15); handles p in {ps, ps+4, ps+8, ps+12},
    // u in [uq*16, uq*16+16). Partial sums reduced across uq via LDS (reusing R).
    {
        int uq = t >> 6, ps = (t >> 4) & 3, vg = t & 15;
        int p0 = ps, p1 = ps + 4, p2 = ps + 8, p3 = ps + 12;
        int i0 = (p0 * (uq << 4)) & 63;
        int i1 = (p1 * (uq << 4)) & 63;
        int i2 = (p2 * (uq << 4)) & 63;
        int i3 = (p3 * (uq << 4)) & 63;
        float4 a0 = {0.f,0.f,0.f,0.f}, a1 = a0, a2 = a0, a3 = a0;
        int ubase = (uq << 4) * 16 + vg;
        for (int uu = 0; uu < 16; ++uu) {
            float4 rv = R4[ubase + uu * 16];
            if (p0 < n) { float c = cyc64L[i0];
                a0.x += c*rv.x; a0.y += c*rv.y; a0.z += c*rv.z; a0.w += c*rv.w; }
            if (p1 < n) { float c = cyc64L[i1];
                a1.x += c*rv.x; a1.y += c*rv.y; a1.z += c*rv.z; a1.w += c*rv.w; }
            if (p2 < n) { float c = cyc64L[i2];
                a2.x += c*rv.x; a2.y += c*rv.y; a2.z += c*rv.z; a2.w += c*rv.w; }
            if (p3 < n) { float c = cyc64L[i3];
                a3.x += c*rv.x; a3.y += c*rv.y; a3.z += c*rv.z; a3.w += c*rv.w; }
            i0 = (i0 + p0) & 63; i1 = (i1 + p1) & 63;
            i2 = (i2 + p2) & 63; i3 = (i3 + p3) & 63;
        }
        __syncthreads();            // all R reads complete before reuse as P
        float4* P4 = R4;            // P[uq][p][vg], 4*16*16 float4 = 16 KB
        int pb = (uq << 8) + vg;
        if (p0 < n) P4[pb + p0 * 16] = a0;
        if (p1 < n) P4[pb + p1 * 16] = a1;
        if (p2 < n) P4[pb + p2 * 16] = a2;
        if (p3 < n) P4[pb + p3 * 16] = a3;
        __syncthreads();
        int pr = t >> 4, vr = t & 15;
        if (pr < n) {
            float4 q0 = P4[pr * 16 + vr];
            float4 q1 = P4[256 + pr * 16 + vr];
            float4 q2 = P4[512 + pr * 16 + vr];
            float4 q3 = P4[768 + pr * 16 + vr];
            float4 s;
            s.x = (q0.x + q1.x) + (q2.x + q3.x);
            s.y = (q0.y + q1.y) + (q2.y + q3.y);
            s.z = (q0.z + q1.z) + (q2.z + q3.z);
            s.w = (q0.w + q1.w) + (q2.w + q3.w);
            *(float4*)&M1[pr * 68 + vr * 4] = s;
        }
    }
    __syncthreads();

    int p = 0, q = 0;
    if (t < nn) { p = t / n; q = t - p * n; }

    // stage 2: H[p][q] = sum_v M1[p][v] * cas64(q*v)
    if (t < nn) {
        float acc = 0.f;
        int idx = 0;
        for (int v = 0; v < 64; ++v) {
            acc += M1[p * 68 + v] * cyc64L[idx];
            idx = (idx + q) & 63;
        }
        H[t] = acc;
    }
    __syncthreads();

    // stage 3: true 2-D DHT of H (n x n) = row-column + correction
    if (t < nn) {
        float acc = 0.f;
        int idx = 0;
        for (int v = 0; v < n; ++v) {
            acc += H[p * n + v] * cnL[idx];
            idx += q; if (idx >= n) idx -= n;
        }
        T1[p * n + q] = acc;
    }
    __syncthreads();
    if (t < nn) {
        float acc = 0.f;
        int idx = 0;
        for (int u = 0; u < n; ++u) {
            acc += T1[u * n + q] * cnL[idx];
            idx += p; if (idx >= n) idx -= n;
        }
        T2[t] = acc;
    }
    __syncthreads();
    if (t < nn) {
        int pf = (p == 0) ? 0 : n - p;
        int qf = (q == 0) ? 0 : n - q;
        H[t] = 0.5f * (T2[p * n + q] + T2[pf * n + q] + T2[p * n + qf] - T2[pf * n + qf]);
    }
    __syncthreads();

    if (t < nn) {
        int fk = (t == 0) ? 0 : nn - t;
        float a = H[t], c = H[fk];
        size_t o = (((size_t)(b * 16 + r)) * CIN + i) * 256 + t;
        Xe[o] = 0.5f * (a + c);
        Xo[o] = 0.5f * (a - c);
    }
}

// dht2 of weights[:, :, :n, :n] for ALL n=1..16 in one 1024-block grid
// (removes 16K-block dispatch + the `used` dependency; W tile loaded once).
__global__ void k_wt(const float* __restrict__ wts, const float* __restrict__ cycN,
                     float* __restrict__ Y) {
    int io = blockIdx.x;
    int t = threadIdx.x;
    __shared__ float Wt[256];
    __shared__ float T1[256];
    __shared__ float T2[256];
    __shared__ float cnL[16];
    Wt[t] = wts[(size_t)io * 256 + t];
    for (int n = 1; n <= NMAX; ++n) {
        int nn = n * n;
        __syncthreads();                       // Wt ready / prev-iter T2 reads done
        if (t < n) cnL[t] = cycN[(n * (n - 1)) / 2 + t];
        __syncthreads();
        int p = 0, q = 0;
        if (t < nn) { p = t / n; q = t - p * n; }
        if (t < nn) {
            float acc = 0.f;
            int idx = 0;
            for (int v = 0; v < n; ++v) {
                acc += Wt[p * 16 + v] * cnL[idx];
                idx += q; if (idx >= n) idx -= n;
            }
            T1[p * n + q] = acc;
        }
        __syncthreads();
        if (t < nn) {
            float acc = 0.f;
            int idx = 0;
            for (int u = 0; u < n; ++u) {
                acc += T1[u * n + q] * cnL[idx];
                idx += p; if (idx >= n) idx -= n;
            }
            T2[t] = acc;
        }
        __syncthreads();
        if (t < nn) {
            int pf = (p == 0) ? 0 : n - p;
            int qf = (q == 0) ? 0 : n - q;
            float v = 0.5f * (T2[p * n + q] + T2[pf * n + q] + T2[p * n + qf] - T2[pf * n + qf]);
            int m = n - 1;
            int ps2 = m * (m + 1) * (2 * m + 1) / 6;
            Y[(size_t)1024 * ps2 + (size_t)io * nn + t] = v;
        }
    }
}

// Z[o,k] = sum_i Xe[i,k]*Y[io,k] + Xo[i,k]*Y[io,flip(k)].
__global__ void k_z(const float* __restrict__ Xe, const float* __restrict__ Xo,
                    const float* __restrict__ Y, const float* __restrict__ avg,
                    float* __restrict__ Z) {
    int br = blockIdx.y;
    int og = blockIdx.x * 4;
    int b = br >> 4, r = br & 15;
    int n = region_n(avg, r, b);
    int nn = n * n;
    int t = threadIdx.x;
    if (t >= nn) return;
    int m = n - 1;
    int ps2 = m * (m + 1) * (2 * m + 1) / 6;
    const float* Yb = Y + (size_t)1024 * ps2;
    int fk = (t == 0) ? 0 : nn - t;
    float acc[4] = {0.f, 0.f, 0.f, 0.f};
    size_t xbase = (size_t)br * CIN * 256;
#pragma unroll 2
    for (int i = 0; i < CIN; ++i) {
        float xe = Xe[xbase + i * 256 + t];
        float xo = Xo[xbase + i * 256 + t];
        const float* yi = Yb + (size_t)(i * COUT + og) * nn;
#pragma unroll
        for (int oo = 0; oo < 4; ++oo) {
            acc[oo] += xe * yi[oo * nn + t] + xo * yi[oo * nn + fk];
        }
    }
    size_t zbase = (size_t)br * COUT * 256;
#pragma unroll
    for (int oo = 0; oo < 4; ++oo) Z[zbase + (og + oo) * 256 + t] = acc[oo];
}

// One block per (o, r, b): inverse dht2 via row-column + correction (/n^2),
// then n->64 separable expansion (/4096). Final stage hoists the E1 read:
// p-outer loop, one ds_read_b128 per p, 4 row-accumulators per thread.
__global__ void k_out(const float* __restrict__ Z, const float* __restrict__ avg,
                      const float* __restrict__ cyc64, const float* __restrict__ cycN,
                      float* __restrict__ out) {
    int o = blockIdx.x, r = blockIdx.y, b = blockIdx.z;
    int n = region_n(avg, r, b);
    int nn = n * n;
    int t = threadIdx.x;
    int br = b * 16 + r;

    __shared__ float Zs[256];
    __shared__ float T1[256];
    __shared__ float T2[256];
    __shared__ float Bk[256];
    __shared__ __align__(16) float E1[16 * 64];
    __shared__ float cyc64L[64];
    __shared__ float cnL[16];

    if (t < 64) cyc64L[t] = cyc64[t];
    if (t < n)  cnL[t] = cycN[(n * (n - 1)) / 2 + t];
    if (t < nn) Zs[t] = Z[((size_t)br * COUT + o) * 256 + t];
    __syncthreads();

    int p = 0, q = 0;
    if (t < nn) { p = t / n; q = t - p * n; }

    if (t < nn) {
        float acc = 0.f;
        int idx = 0;
        for (int v = 0; v < n; ++v) {
            acc += Zs[p * n + v] * cnL[idx];
            idx += q; if (idx >= n) idx -= n;
        }
        T1[p * n + q] = acc;
    }
    __syncthreads();
    if (t < nn) {
        float acc = 0.f;
        int idx = 0;
        for (int u = 0; u < n; ++u) {
            acc += T1[u * n + q] * cnL[idx];
            idx += p; if (idx >= n) idx -= n;
        }
        T2[t] = acc;
    }
    __syncthreads();
    if (t < nn) {
        int pf = (p == 0) ? 0 : n - p;
        int qf = (q == 0) ? 0 : n - q;
        Bk[t] = 0.5f * (T2[p * n + q] + T2[pf * n + q] + T2[p * n + qf] - T2[pf * n + qf])
                / (float)nn;
    }
    __syncthreads();

    // E1[p][v] = sum_q Bk[p*n+q] * cas64(q*v)   (wave-uniform p: Bk read is broadcast)
    for (int mm = t; mm < n * 64; mm += 256) {
        int pp = mm >> 6, v = mm & 63;
        float acc = 0.f;
        int idx = 0;
        for (int qq = 0; qq < n; ++qq) {
            acc += Bk[pp * n + qq] * cyc64L[idx];
            idx = (idx + v) & 63;
        }
        E1[pp * 64 + v] = acc;
    }
    __syncthreads();

    // out[u][v] = (1/4096) sum_p E1[p][v] * cas64(p*u); p-outer, 4 u-rows/thread.
    int ri = r >> 2, rj = r & 3;
    float* ob = out + (((size_t)(b * COUT + o)) * SS + ri * REG) * SS + rj * REG;
    const float4* E14 = (const float4*)E1;
    const float inv = 1.0f / 4096.0f;
    int u0 = t >> 4, vg = t & 15;
    int uA = u0, uB = 16 + u0, uC = 32 + u0, uD = 48 + u0;
    int iA = 0, iB = 0, iC = 0, iD = 0;
    float4 aA = {0.f,0.f,0.f,0.f}, aB = aA, aC = aA, aD = aA;
    for (int pp = 0; pp < n; ++pp) {
        float4 e = E14[pp * 16 + vg];
        float cA = cyc64L[iA]; iA = (iA + uA) & 63;
        float cB = cyc64L[iB]; iB = (iB + uB) & 63;
        float cC = cyc64L[iC]; iC = (iC + uC) & 63;
        float cD = cyc64L[iD]; iD = (iD + uD) & 63;
        aA.x += cA*e.x; aA.y += cA*e.y; aA.z += cA*e.z; aA.w += cA*e.w;
        aB.x += cB*e.x; aB.y += cB*e.y; aB.z += cB*e.z; aB.w += cB*e.w;
        aC.x += cC*e.x; aC.y += cC*e.y; aC.z += cC*e.z; aC.w += cC*e.w;
        aD.x += cD*e.x; aD.y += cD*e.y; aD.z += cD*e.z; aD.w += cD*e.w;
    }
    aA.x *= inv; aA.y *= inv; aA.z *= inv; aA.w *= inv;
    aB.x *= inv; aB.y *= inv; aB.z *= inv; aB.w *= inv;
    aC.x *= inv; aC.y *= inv; aC.z *= inv; aC.w *= inv;
    aD.x *= inv; aD.y *= inv; aD.z *= inv; aD.w *= inv;
    *(float4*)(ob + (size_t)uA * SS + vg * 4) = aA;
    *(float4*)(ob + (size_t)uB * SS + vg * 4) = aB;
    *(float4*)(ob + (size_t)uC * SS + vg * 4) = aC;
    *(float4*)(ob + (size_t)uD * SS + vg * 4) = aD;
}

extern "C" void kernel_launch(void* const* d_in, const int* in_sizes, int n_in,
                              void* d_out, int out_size, void* d_ws, size_t ws_size,
                              hipStream_t stream) {
    const float* x   = (const float*)d_in[0];
    const float* err = (const float*)d_in[1];
    const float* wts = (const float*)d_in[2];
    float* out = (float*)d_out;
    char* ws = (char*)d_ws;

    float* avg   = (float*)(ws + AVG_OFF);
    float* cyc64 = (float*)(ws + C64_OFF);
    float* cycN  = (float*)(ws + CN_OFF);
    float* Y     = (float*)(ws + Y_OFF);
    float* Xe    = (float*)(ws + XE_OFF);
    float* Xo    = (float*)(ws + XO_OFF);
    float* Z     = (float*)(ws + Z_OFF);

    k_avg<<<dim3(17, NB), 256, 0, stream>>>(err, avg, cyc64, cycN);
    k_wt<<<dim3(CIN * COUT), 256, 0, stream>>>(wts, cycN, Y);
    k_fwd<<<dim3(CIN, 16, NB), 256, 0, stream>>>(x, avg, cyc64, cycN, Xe, Xo);
    k_z<<<dim3(8, 128), 256, 0, stream>>>(Xe, Xo, Y, avg, Z);
    k_out<<<dim3(COUT, 16, NB), 256, 0, stream>>>(Z, avg, cyc64, cycN, out);
}

// Round 2
// 181.210 us; speedup vs baseline: 1.0079x; 1.0079x over previous
//
#include <hip/hip_runtime.h>
#include <math.h>

// Problem constants (from reference): B=8, Cin=32, Cout=32, S=256,
// REGION=64, OVERLAP=0 -> 4x4 regions, MAX_M=16.
#define NB 8
#define CIN 32
#define COUT 32
#define SS 256
#define REG 64
#define NMAX 16

// Workspace layout (bytes):
#define AVG_OFF   0
#define C64_OFF   4096
#define CN_OFF    4352
#define Y_OFF     8192            // 1024 io * 1496 * 4B ~ 6.13 MB
#define YF_OFF    (8u << 20)      // pre-flipped copy of Y, same layout
#define XE_OFF    (16u << 20)     // 4 MB
#define XO_OFF    (20u << 20)     // 4 MB

// Per-block recomputation of the region's mode count n.
// MUST be bit-identical everywhere so every consumer agrees.
__device__ __forceinline__ int region_n(const float* __restrict__ avg, int r, int b) {
    float mn = avg[r * 8], mx = mn;
    for (int bb = 1; bb < NB; ++bb) {
        float v = avg[r * 8 + bb];
        mn = fminf(mn, v);
        mx = fmaxf(mx, v);
    }
    float d = mx - mn;
    bool ok = ((double)d > 1e-8);
    float norm = ok ? (avg[r * 8 + b] - mn) / d : 0.0f;
    float tt = norm * 15.0f;
    int nv = (int)tt + 1;
    return nv > NMAX ? NMAX : nv;
}

// One launch, three block roles:
//   bx <  128 : region means (r = bx&15, b = bx>>4)
//   bx == 128 : global cas tables (for k_fwd / k_zout)
//   bx >  128 : weight DHTs, io = bx-129; builds its own local cas table
//               (136 parallel f64 sincos) so it has no cross-block dependency.
// Writes Y and the pre-flipped Yf.
__global__ void k_prep(const float* __restrict__ err, const float* __restrict__ wts,
                       float* __restrict__ avg, float* __restrict__ cyc64,
                       float* __restrict__ cycN, float* __restrict__ Y,
                       float* __restrict__ Yf) {
    int bx = blockIdx.x;
    int t = threadIdx.x;

    if (bx < 128) {
        int r = bx & 15, b = bx >> 4;
        int ri = r >> 2, rj = r & 3;
        const float* base = err + ((size_t)b * SS + ri * REG) * SS + rj * REG;
        double s = 0.0;
        for (int it = 0; it < 16; ++it) {
            int u = it * 4 + (t >> 6);
            int v = t & 63;
            s += (double)base[(size_t)u * SS + v];
        }
        __shared__ double sm[256];
        sm[t] = s;
        __syncthreads();
        for (int w = 128; w > 0; w >>= 1) {
            if (t < w) sm[t] += sm[t + w];
            __syncthreads();
        }
        if (t == 0) avg[r * 8 + b] = (float)(sm[0] / 4096.0);
        return;
    }

    if (bx == 128) {
        if (t < 64) {
            double a = (2.0 * M_PI / 64.0) * (double)t;
            cyc64[t] = (float)(cos(a) + sin(a));
        } else if (t < 64 + 136) {
            int e = t - 64;
            int n = 1;
            while (n * (n + 1) / 2 <= e) ++n;
            int j = e - n * (n - 1) / 2;
            double a = (2.0 * M_PI / (double)n) * (double)j;
            cycN[e] = (float)(cos(a) + sin(a));
        }
        return;
    }

    // ---- weight block ----
    int io = bx - 129;
    __shared__ float Wt[256];
    __shared__ float T1[256];
    __shared__ float T2[256];
    __shared__ float cnAll[136];
    if (t < 136) {
        int e = t;
        int n = 1;
        while (n * (n + 1) / 2 <= e) ++n;
        int j = e - n * (n - 1) / 2;
        double a = (2.0 * M_PI / (double)n) * (double)j;
        cnAll[e] = (float)(cos(a) + sin(a));
    }
    Wt[t] = wts[(size_t)io * 256 + t];
    __syncthreads();

    for (int n = 1; n <= NMAX; ++n) {
        int nn = n * n;
        const float* cnL = &cnAll[(n * (n - 1)) / 2];
        int p = 0, q = 0;
        if (t < nn) { p = t / n; q = t - p * n; }
        if (t < nn) {
            float acc = 0.f;
            int idx = 0;
            for (int v = 0; v < n; ++v) {
                acc += Wt[p * 16 + v] * cnL[idx];
                idx += q; if (idx >= n) idx -= n;
            }
            T1[p * n + q] = acc;
        }
        __syncthreads();
        if (t < nn) {
            float acc = 0.f;
            int idx = 0;
            for (int u = 0; u < n; ++u) {
                acc += T1[u * n + q] * cnL[idx];
                idx += p; if (idx >= n) idx -= n;
            }
            T2[t] = acc;
        }
        __syncthreads();
        if (t < nn) {
            int pf = (p == 0) ? 0 : n - p;
            int qf = (q == 0) ? 0 : n - q;
            float v = 0.5f * (T2[p * n + q] + T2[pf * n + q] + T2[p * n + qf] - T2[pf * n + qf]);
            int m = n - 1;
            int ps2 = m * (m + 1) * (2 * m + 1) / 6;
            size_t basei = (size_t)1024 * ps2 + (size_t)io * nn;
            Y[basei + t] = v;
            int fk = (t == 0) ? 0 : nn - t;
            Yf[basei + fk] = v;
        }
        __syncthreads();  // T2 reads done before next iter's stage-2 rewrite
    }
}

// One block per (i, r, b): n-corner separable DHT of the 64x64 region, then
// true n x n dht2 via row-column + correction, then Xe/Xo split. 256 threads.
// (unchanged from previous round — verified)
__global__ void k_fwd(const float* __restrict__ x, const float* __restrict__ avg,
                      const float* __restrict__ cyc64, const float* __restrict__ cycN,
                      float* __restrict__ Xe, float* __restrict__ Xo) {
    int i = blockIdx.x, r = blockIdx.y, b = blockIdx.z;
    int n = region_n(avg, r, b);
    int nn = n * n;
    int ri = r >> 2, rj = r & 3;
    int t = threadIdx.x;

    __shared__ __align__(16) float R[64 * 64];      // reused as partial buffer P
    __shared__ __align__(16) float M1[16 * 68];
    __shared__ float H[256];
    __shared__ float T1[256];
    __shared__ float T2[256];
    __shared__ float cyc64L[64];
    __shared__ float cnL[16];

    if (t < 64) cyc64L[t] = cyc64[t];
    if (t < n)  cnL[t] = cycN[(n * (n - 1)) / 2 + t];

    const float* base = x + (((size_t)(b * CIN + i)) * SS + ri * REG) * SS + rj * REG;
    float4* R4 = (float4*)R;
    {
        int u0 = t >> 4, c4 = t & 15;
        for (int it = 0; it < 4; ++it) {
            int u = it * 16 + u0;
            R4[u * 16 + c4] = *(const float4*)(base + (size_t)u * SS + c4 * 4);
        }
    }
    __syncthreads();

    // stage 1: M1[p][v] = sum_u cas64(p*u) * R[u][v], p < n.
    {
        int uq = t >> 6, ps = (t >> 4) & 3, vg = t & 15;
        int p0 = ps, p1 = ps + 4, p2 = ps + 8, p3 = ps + 12;
        int i0 = (p0 * (uq << 4)) & 63;
        int i1 = (p1 * (uq << 4)) & 63;
        int i2 = (p2 * (uq << 4)) & 63;
        int i3 = (p3 * (uq << 4)) & 63;
        float4 a0 = {0.f,0.f,0.f,0.f}, a1 = a0, a2 = a0, a3 = a0;
        int ubase = (uq << 4) * 16 + vg;
        for (int uu = 0; uu < 16; ++uu) {
            float4 rv = R4[ubase + uu * 16];
            if (p0 < n) { float c = cyc64L[i0];
                a0.x += c*rv.x; a0.y += c*rv.y; a0.z += c*rv.z; a0.w += c*rv.w; }
            if (p1 < n) { float c = cyc64L[i1];
                a1.x += c*rv.x; a1.y += c*rv.y; a1.z += c*rv.z; a1.w += c*rv.w; }
            if (p2 < n) { float c = cyc64L[i2];
                a2.x += c*rv.x; a2.y += c*rv.y; a2.z += c*rv.z; a2.w += c*rv.w; }
            if (p3 < n) { float c = cyc64L[i3];
                a3.x += c*rv.x; a3.y += c*rv.y; a3.z += c*rv.z; a3.w += c*rv.w; }
            i0 = (i0 + p0) & 63; i1 = (i1 + p1) & 63;
            i2 = (i2 + p2) & 63; i3 = (i3 + p3) & 63;
        }
        __syncthreads();            // all R reads complete before reuse as P
        float4* P4 = R4;            // P[uq][p][vg]
        int pb = (uq << 8) + vg;
        if (p0 < n) P4[pb + p0 * 16] = a0;
        if (p1 < n) P4[pb + p1 * 16] = a1;
        if (p2 < n) P4[pb + p2 * 16] = a2;
        if (p3 < n) P4[pb + p3 * 16] = a3;
        __syncthreads();
        int pr = t >> 4, vr = t & 15;
        if (pr < n) {
            float4 q0 = P4[pr * 16 + vr];
            float4 q1 = P4[256 + pr * 16 + vr];
            float4 q2 = P4[512 + pr * 16 + vr];
            float4 q3 = P4[768 + pr * 16 + vr];
            float4 s;
            s.x = (q0.x + q1.x) + (q2.x + q3.x);
            s.y = (q0.y + q1.y) + (q2.y + q3.y);
            s.z = (q0.z + q1.z) + (q2.z + q3.z);
            s.w = (q0.w + q1.w) + (q2.w + q3.w);
            *(float4*)&M1[pr * 68 + vr * 4] = s;
        }
    }
    __syncthreads();

    int p = 0, q = 0;
    if (t < nn) { p = t / n; q = t - p * n; }

    // stage 2: H[p][q] = sum_v M1[p][v] * cas64(q*v)
    if (t < nn) {
        float acc = 0.f;
        int idx = 0;
        for (int v = 0; v < 64; ++v) {
            acc += M1[p * 68 + v] * cyc64L[idx];
            idx = (idx + q) & 63;
        }
        H[t] = acc;
    }
    __syncthreads();

    // stage 3: true 2-D DHT of H (n x n) = row-column + correction
    if (t < nn) {
        float acc = 0.f;
        int idx = 0;
        for (int v = 0; v < n; ++v) {
            acc += H[p * n + v] * cnL[idx];
            idx += q; if (idx >= n) idx -= n;
        }
        T1[p * n + q] = acc;
    }
    __syncthreads();
    if (t < nn) {
        float acc = 0.f;
        int idx = 0;
        for (int u = 0; u < n; ++u) {
            acc += T1[u * n + q] * cnL[idx];
            idx += p; if (idx >= n) idx -= n;
        }
        T2[t] = acc;
    }
    __syncthreads();
    if (t < nn) {
        int pf = (p == 0) ? 0 : n - p;
        int qf = (q == 0) ? 0 : n - q;
        H[t] = 0.5f * (T2[p * n + q] + T2[pf * n + q] + T2[p * n + qf] - T2[pf * n + qf]);
    }
    __syncthreads();

    if (t < nn) {
        int fk = (t == 0) ? 0 : nn - t;
        float a = H[t], c = H[fk];
        size_t o = (((size_t)(b * 16 + r)) * CIN + i) * 256 + t;
        Xe[o] = 0.5f * (a + c);
        Xo[o] = 0.5f * (a - c);
    }
}

// Fused channel-mix + inverse: one block per (og, br); computes Z for 4
// consecutive outputs in registers (keeps k_z's 4-way Xe/Xo reuse), stores
// to LDS, then serially runs the inverse dht2 + n->64 expansion for each o.
// Removes the Z global round-trip, one launch gap, and k_z's separate pass.
__global__ void k_zout(const float* __restrict__ Xe, const float* __restrict__ Xo,
                       const float* __restrict__ Y, const float* __restrict__ Yf,
                       const float* __restrict__ avg, const float* __restrict__ cyc64,
                       const float* __restrict__ cycN, float* __restrict__ out) {
    int og = blockIdx.x * 4;
    int br = blockIdx.y;
    int b = br >> 4, r = br & 15;
    int n = region_n(avg, r, b);
    int nn = n * n;
    int t = threadIdx.x;

    __shared__ float zbuf[4][256];
    __shared__ float T1[256];
    __shared__ float T2[256];
    __shared__ float Bk[256];
    __shared__ __align__(16) float E1[16 * 64];
    __shared__ __align__(16) float CTo[16 * 16 * 4];   // [p][u0] -> float4 of cas(p*(u0+16k))
    __shared__ float cyc64L[64];
    __shared__ float cnL[16];

    if (t < 64) cyc64L[t] = cyc64[t];
    if (t < n)  cnL[t] = cycN[(n * (n - 1)) / 2 + t];
    __syncthreads();

    // coefficient table for the final expansion: 1 b128 read replaces 4 b32
    {
        int pp = t >> 4, u0 = t & 15;
        float4 c;
        c.x = cyc64L[(pp * u0) & 63];
        c.y = cyc64L[(pp * (u0 + 16)) & 63];
        c.z = cyc64L[(pp * (u0 + 32)) & 63];
        c.w = cyc64L[(pp * (u0 + 48)) & 63];
        *(float4*)&CTo[t * 4] = c;
    }

    // ---- z-phase: Z[og+oo][k] = sum_i Xe[i,k]*Y[io,k] + Xo[i,k]*Y[io,flip(k)]
    if (t < nn) {
        int m = n - 1;
        int ps2 = m * (m + 1) * (2 * m + 1) / 6;
        const float* Yb  = Y  + (size_t)1024 * ps2;
        const float* Yfb = Yf + (size_t)1024 * ps2;
        float a0 = 0.f, a1 = 0.f, a2 = 0.f, a3 = 0.f;
        size_t xbase = (size_t)br * CIN * 256;
        for (int i = 0; i < CIN; ++i) {
            float xe = Xe[xbase + i * 256 + t];
            float xo = Xo[xbase + i * 256 + t];
            const float* yp  = Yb  + (size_t)(i * COUT + og) * nn + t;
            const float* yfp = Yfb + (size_t)(i * COUT + og) * nn + t;
            a0 += xe * yp[0]      + xo * yfp[0];
            a1 += xe * yp[nn]     + xo * yfp[nn];
            a2 += xe * yp[2 * nn] + xo * yfp[2 * nn];
            a3 += xe * yp[3 * nn] + xo * yfp[3 * nn];
        }
        zbuf[0][t] = a0; zbuf[1][t] = a1; zbuf[2][t] = a2; zbuf[3][t] = a3;
    }

    int p = 0, q = 0;
    if (t < nn) { p = t / n; q = t - p * n; }
    int ri = r >> 2, rj = r & 3;
    int u0 = t >> 4, vg = t & 15;
    const float4* E14 = (const float4*)E1;
    const float4* CT4 = (const float4*)CTo;
    const float inv = 1.0f / 4096.0f;

    for (int oo = 0; oo < 4; ++oo) {
        __syncthreads();   // zbuf ready (oo=0) / prev E1 reads done (oo>0)
        if (t < nn) {
            float acc = 0.f;
            int idx = 0;
            for (int v = 0; v < n; ++v) {
                acc += zbuf[oo][p * n + v] * cnL[idx];
                idx += q; if (idx >= n) idx -= n;
            }
            T1[p * n + q] = acc;
        }
        __syncthreads();
        if (t < nn) {
            float acc = 0.f;
            int idx = 0;
            for (int u = 0; u < n; ++u) {
                acc += T1[u * n + q] * cnL[idx];
                idx += p; if (idx >= n) idx -= n;
            }
            T2[t] = acc;
        }
        __syncthreads();
        if (t < nn) {
            int pf = (p == 0) ? 0 : n - p;
            int qf = (q == 0) ? 0 : n - q;
            Bk[t] = 0.5f * (T2[p * n + q] + T2[pf * n + q] + T2[p * n + qf] - T2[pf * n + qf])
                    / (float)nn;
        }
        __syncthreads();
        // E1[p][v] = sum_q Bk[p*n+q] * cas64(q*v)
        for (int mm = t; mm < n * 64; mm += 256) {
            int pp = mm >> 6, v = mm & 63;
            float acc = 0.f;
            int idx = 0;
            for (int qq = 0; qq < n; ++qq) {
                acc += Bk[pp * n + qq] * cyc64L[idx];
                idx = (idx + v) & 63;
            }
            E1[pp * 64 + v] = acc;
        }
        __syncthreads();
        // out[u][v] = (1/4096) sum_p E1[p][v] * cas64(p*u); p-outer, 4 u-rows/thread.
        float* ob = out + (((size_t)(b * COUT + og + oo)) * SS + ri * REG) * SS + rj * REG;
        float4 aA = {0.f,0.f,0.f,0.f}, aB = aA, aC = aA, aD = aA;
        for (int pp = 0; pp < n; ++pp) {
            float4 e = E14[pp * 16 + vg];
            float4 c = CT4[pp * 16 + u0];
            aA.x += c.x*e.x; aA.y += c.x*e.y; aA.z += c.x*e.z; aA.w += c.x*e.w;
            aB.x += c.y*e.x; aB.y += c.y*e.y; aB.z += c.y*e.z; aB.w += c.y*e.w;
            aC.x += c.z*e.x; aC.y += c.z*e.y; aC.z += c.z*e.z; aC.w += c.z*e.w;
            aD.x += c.w*e.x; aD.y += c.w*e.y; aD.z += c.w*e.z; aD.w += c.w*e.w;
        }
        aA.x *= inv; aA.y *= inv; aA.z *= inv; aA.w *= inv;
        aB.x *= inv; aB.y *= inv; aB.z *= inv; aB.w *= inv;
        aC.x *= inv; aC.y *= inv; aC.z *= inv; aC.w *= inv;
        aD.x *= inv; aD.y *= inv; aD.z *= inv; aD.w *= inv;
        *(float4*)(ob + (size_t)(u0)      * SS + vg * 4) = aA;
        *(float4*)(ob + (size_t)(16 + u0) * SS + vg * 4) = aB;
        *(float4*)(ob + (size_t)(32 + u0) * SS + vg * 4) = aC;
        *(float4*)(ob + (size_t)(48 + u0) * SS + vg * 4) = aD;
    }
}

extern "C" void kernel_launch(void* const* d_in, const int* in_sizes, int n_in,
                              void* d_out, int out_size, void* d_ws, size_t ws_size,
                              hipStream_t stream) {
    const float* x   = (const float*)d_in[0];
    const float* err = (const float*)d_in[1];
    const float* wts = (const float*)d_in[2];
    float* out = (float*)d_out;
    char* ws = (char*)d_ws;

    float* avg   = (float*)(ws + AVG_OFF);
    float* cyc64 = (float*)(ws + C64_OFF);
    float* cycN  = (float*)(ws + CN_OFF);
    float* Y     = (float*)(ws + Y_OFF);
    float* Yf    = (float*)(ws + YF_OFF);
    float* Xe    = (float*)(ws + XE_OFF);
    float* Xo    = (float*)(ws + XO_OFF);

    k_prep<<<dim3(128 + 1 + CIN * COUT), 256, 0, stream>>>(err, wts, avg, cyc64, cycN, Y, Yf);
    k_fwd<<<dim3(CIN, 16, NB), 256, 0, stream>>>(x, avg, cyc64, cycN, Xe, Xo);
    k_zout<<<dim3(8, 128), 256, 0, stream>>>(Xe, Xo, Y, Yf, avg, cyc64, cycN, out);
}